// Round 7
// baseline (571.087 us; speedup 1.0000x reference)
//
#include <hip/hip_runtime.h>
#include <hip/hip_bf16.h>

#define N_NODES  50000
#define N_EDGES  600000
#define D_IN     128
#define H        64
#define N_GRAPHS 500
#define MAXDEG   48               // Poisson(12); P(deg>48) negligible (validated r2/r5)

#define NBLK 768                  // 3 blocks/CU while launch_bounds guarantees HW
#define NTHR 256                  //   capacity 4/CU -> co-residency slack (no deadlock)
#define NW   (NBLK * NTHR)        // 196608 threads

// phase B scatter: 96 edge-chunks x 8 dst-range shards = 768 blocks
#define SCHUNKS 96
#define EPC     (N_EDGES / SCHUNKS)   // 6250 exactly
#define NPS     (N_NODES / 8)         // 6250 nodes per dst shard

// phase C gather: 6 waves per graph
#define GSUB   6
#define GWAVES (N_GRAPHS * GSUB)      // 3000 (of 3072 waves)

// ws layout (bytes)
#define OF_CTR  0                 // 4 barrier counters (memset to 0 pre-launch)
#define OF_DEG  64                // int[50000]            -> 200064
#define OF_PN   200704            // float[500*128]        -> 456704
#define OF_PX   456704            // float[500*128]        -> 712704
#define OF_GST  712704            // int[501]              -> 714708
#define OF_COL  716800            // ushort[50000*48]      -> 5516800
#define OF_XB   5516800           // ushort[50000*128]     -> 18316800
#define ZERO_Q  44540             // (OF_GST-OF_DEG)/16 uint4s: deg+pad+Pn+Px

__device__ __forceinline__ float bflo(unsigned int u) { return __uint_as_float(u << 16); }
__device__ __forceinline__ float bfhi(unsigned int u) { return __uint_as_float(u & 0xffff0000u); }

__device__ __forceinline__ void gbar(int* ctr, int idx) {
    __syncthreads();
    if (threadIdx.x == 0) {
        __threadfence();
        __hip_atomic_fetch_add(&ctr[idx], 1, __ATOMIC_ACQ_REL, __HIP_MEMORY_SCOPE_AGENT);
        while (__hip_atomic_load(&ctr[idx], __ATOMIC_ACQUIRE, __HIP_MEMORY_SCOPE_AGENT) < NBLK)
            __builtin_amdgcn_s_sleep(1);
        __threadfence();
    }
    __syncthreads();
}

// ---------------------------------------------------------------------------
// One persistent kernel, 4 phases separated by software grid barriers.
__global__ __launch_bounds__(NTHR, 4) void gnn_kernel(
        const float* __restrict__ x, const int* __restrict__ ei,
        const int* __restrict__ batch,
        const float* __restrict__ Wl, const float* __restrict__ bl,
        const float* __restrict__ Wr,
        const float* __restrict__ W0, const float* __restrict__ b0,
        const float* __restrict__ W1, const float* __restrict__ b1,
        const float* __restrict__ W2, const float* __restrict__ b2,
        const float* __restrict__ W3, const float* __restrict__ b3,
        char* __restrict__ ws, float* __restrict__ out) {
    int* ctr             = (int*)(ws + OF_CTR);
    int* deg             = (int*)(ws + OF_DEG);
    float* Pn            = (float*)(ws + OF_PN);
    float* Px            = (float*)(ws + OF_PX);
    int* gstart          = (int*)(ws + OF_GST);
    unsigned short* col  = (unsigned short*)(ws + OF_COL);
    unsigned short* xb   = (unsigned short*)(ws + OF_XB);

    int bid  = blockIdx.x, t = threadIdx.x;
    int gtid = bid * NTHR + t;
    int wave = t >> 6, lane = t & 63;

    __shared__ float sp[D_IN], sx[D_IN], hs[H], a0[32], a1[16], a2[8];

    const int* src = ei;
    const int* dst = ei + N_EDGES;

    // ---- Phase A: zero deg + Pn + Px ------------------------------------
    {
        uint4 z = make_uint4(0, 0, 0, 0);
        uint4* zp = (uint4*)(ws + OF_DEG);
        for (int i = gtid; i < ZERO_Q; i += NW) zp[i] = z;
    }
    gbar(ctr, 0);

    // ---- Phase B: conv fp32->bf16, sharded bucket scatter, gstart -------
    {   // conv: 1.6M float4 -> ushort4 tasks
        const float4* xi = (const float4*)x;
        ushort4* xo = (ushort4*)xb;
        for (int i = gtid; i < N_NODES * D_IN / 4; i += NW) {
            float4 f = xi[i];
            ushort4 u;
            u.x = __bfloat16_as_ushort(__float2bfloat16(f.x));
            u.y = __bfloat16_as_ushort(__float2bfloat16(f.y));
            u.z = __bfloat16_as_ushort(__float2bfloat16(f.z));
            u.w = __bfloat16_as_ushort(__float2bfloat16(f.w));
            xo[i] = u;
        }
        // scatter: chunk = bid>>3, dst-range shard = bid&7 (XCD-affinity
        // heuristic for col/deg lines; coverage exact regardless of mapping)
        int shard = bid & 7;
        int chunk = bid >> 3;
        int lo = shard * NPS, hi = lo + NPS;
        int e0 = chunk * EPC, e1 = e0 + EPC;
        for (int e = e0 + t; e < e1; e += NTHR) {
            int d = dst[e];
            if (d >= lo && d < hi) {
                int pos = atomicAdd(&deg[d], 1);
                if (pos < MAXDEG)
                    col[(size_t)d * MAXDEG + pos] = (unsigned short)src[e];
            }
        }
        // gstart: last 8 blocks, binary search over sorted batch
        if (bid >= NBLK - 8) {
            int g = (bid - (NBLK - 8)) * NTHR + t;
            if (g <= N_GRAPHS) {
                int l = 0, h2 = N_NODES;
                while (l < h2) { int m = (l + h2) >> 1; if (batch[m] < g) l = m + 1; else h2 = m; }
                gstart[g] = l;
            }
        }
    }
    gbar(ctr, 1);

    // ---- Phase C: gather (full-row, 8-wide unrolled) + Px ---------------
    {
        int W = bid * 4 + wave;          // global wave id
        if (W < GWAVES) {
            int g = W / GSUB;
            int r = W - g * GSUB;
            int n0 = gstart[g], n1 = gstart[g + 1];
            const unsigned short* xl = xb + 2 * lane;   // lane's feature pair

            float pnx = 0.f, pny = 0.f, pxx = 0.f, pxy = 0.f;
            for (int n = n0 + r; n < n1; n += GSUB) {
                unsigned int um = *(const unsigned int*)(xl + (size_t)n * D_IN);
                pxx += bflo(um); pxy += bfhi(um);

                int d  = deg[n];
                int dl = (d < MAXDEG) ? d : MAXDEG;
                int cidx = (lane < dl) ? (int)col[(size_t)n * MAXDEG + lane] : 0;

                float tx = 0.f, ty = 0.f;
                int j = 0;
                for (; j + 8 <= dl; j += 8) {
                    int s0 = __shfl(cidx, j),     s1 = __shfl(cidx, j + 1);
                    int s2 = __shfl(cidx, j + 2), s3 = __shfl(cidx, j + 3);
                    int s4 = __shfl(cidx, j + 4), s5 = __shfl(cidx, j + 5);
                    int s6 = __shfl(cidx, j + 6), s7 = __shfl(cidx, j + 7);
                    unsigned int u0 = *(const unsigned int*)(xl + (size_t)s0 * D_IN);
                    unsigned int u1 = *(const unsigned int*)(xl + (size_t)s1 * D_IN);
                    unsigned int u2 = *(const unsigned int*)(xl + (size_t)s2 * D_IN);
                    unsigned int u3 = *(const unsigned int*)(xl + (size_t)s3 * D_IN);
                    unsigned int u4 = *(const unsigned int*)(xl + (size_t)s4 * D_IN);
                    unsigned int u5 = *(const unsigned int*)(xl + (size_t)s5 * D_IN);
                    unsigned int u6 = *(const unsigned int*)(xl + (size_t)s6 * D_IN);
                    unsigned int u7 = *(const unsigned int*)(xl + (size_t)s7 * D_IN);
                    tx += bflo(u0) + bflo(u1) + bflo(u2) + bflo(u3)
                        + bflo(u4) + bflo(u5) + bflo(u6) + bflo(u7);
                    ty += bfhi(u0) + bfhi(u1) + bfhi(u2) + bfhi(u3)
                        + bfhi(u4) + bfhi(u5) + bfhi(u6) + bfhi(u7);
                }
                for (; j + 4 <= dl; j += 4) {
                    int s0 = __shfl(cidx, j),     s1 = __shfl(cidx, j + 1);
                    int s2 = __shfl(cidx, j + 2), s3 = __shfl(cidx, j + 3);
                    unsigned int u0 = *(const unsigned int*)(xl + (size_t)s0 * D_IN);
                    unsigned int u1 = *(const unsigned int*)(xl + (size_t)s1 * D_IN);
                    unsigned int u2 = *(const unsigned int*)(xl + (size_t)s2 * D_IN);
                    unsigned int u3 = *(const unsigned int*)(xl + (size_t)s3 * D_IN);
                    tx += bflo(u0) + bflo(u1) + bflo(u2) + bflo(u3);
                    ty += bfhi(u0) + bfhi(u1) + bfhi(u2) + bfhi(u3);
                }
                for (; j < dl; ++j) {
                    int sn = __shfl(cidx, j);
                    unsigned int u = *(const unsigned int*)(xl + (size_t)sn * D_IN);
                    tx += bflo(u); ty += bfhi(u);
                }
                if (d > 0) {
                    float w = __builtin_amdgcn_rcpf((float)d);
                    pnx = fmaf(tx, w, pnx);
                    pny = fmaf(ty, w, pny);
                }
            }
            float* pnp = Pn + (size_t)g * D_IN + 2 * lane;
            float* pxp = Px + (size_t)g * D_IN + 2 * lane;
            atomicAdd(pnp,     pnx); atomicAdd(pnp + 1, pny);
            atomicAdd(pxp,     pxx); atomicAdd(pxp + 1, pxy);
        }
    }
    gbar(ctr, 2);

    // ---- Phase D: per-graph (Pn@Wl + Px@Wr)/ng + bl, then MLP -----------
    if (bid < N_GRAPHS) {
        int g = bid;
        if (t < D_IN)      sp[t] = Pn[(size_t)g * D_IN + t];
        else               sx[t - D_IN] = Px[(size_t)g * D_IN + (t - D_IN)];
        __syncthreads();
        int ng = gstart[g + 1] - gstart[g];
        if (t < H) {
            float acc = 0.f;
            #pragma unroll 8
            for (int d = 0; d < D_IN; ++d)
                acc += sp[d] * Wl[d * H + t] + sx[d] * Wr[d * H + t];
            hs[t] = (ng > 0) ? (acc / (float)ng + bl[t]) : 0.f;  // empty graph -> 0
        }
        __syncthreads();
        if (t < 32) { float a = b0[t]; for (int d = 0; d < H;  ++d) a += hs[d] * W0[d * 32 + t]; a0[t] = fmaxf(a, 0.f); }
        __syncthreads();
        if (t < 16) { float a = b1[t]; for (int d = 0; d < 32; ++d) a += a0[d] * W1[d * 16 + t]; a1[t] = fmaxf(a, 0.f); }
        __syncthreads();
        if (t < 8)  { float a = b2[t]; for (int d = 0; d < 16; ++d) a += a1[d] * W2[d * 8 + t];  a2[t] = fmaxf(a, 0.f); }
        __syncthreads();
        if (t == 0) { float a = b3[0]; for (int d = 0; d < 8;  ++d) a += a2[d] * W3[d]; out[g] = a; }
    }
}

// ---------------------------------------------------------------------------
extern "C" void kernel_launch(void* const* d_in, const int* in_sizes, int n_in,
                              void* d_out, int out_size, void* d_ws, size_t ws_size,
                              hipStream_t stream) {
    const float* x     = (const float*)d_in[0];
    const int*   ei    = (const int*)  d_in[1];   // [2, N_EDGES]: row0=src, row1=dst
    const int*   batch = (const int*)  d_in[2];
    const float* Wl    = (const float*)d_in[3];
    const float* bl    = (const float*)d_in[4];
    const float* Wr    = (const float*)d_in[5];
    const float* W0    = (const float*)d_in[6];
    const float* b0    = (const float*)d_in[7];
    const float* W1    = (const float*)d_in[8];
    const float* b1    = (const float*)d_in[9];
    const float* W2    = (const float*)d_in[10];
    const float* b2    = (const float*)d_in[11];
    const float* W3    = (const float*)d_in[12];
    const float* b3    = (const float*)d_in[13];
    float* out = (float*)d_out;

    // barrier counters must be zero before the kernel (ws is 0xAA-poisoned)
    hipMemsetAsync(d_ws, 0, 64, stream);

    gnn_kernel<<<NBLK, NTHR, 0, stream>>>(
        x, ei, batch, Wl, bl, Wr, W0, b0, W1, b1, W2, b2, W3, b3,
        (char*)d_ws, out);
}

// Round 8
// 165.427 us; speedup vs baseline: 3.4522x; 3.4522x over previous
//
#include <hip/hip_runtime.h>
#include <hip/hip_bf16.h>

#define N_NODES  50000
#define N_EDGES  600000
#define D_IN     128
#define H        64
#define N_GRAPHS 500
#define MAXDEG   48               // Poisson(12); P(deg>48) negligible (validated r2/r5)

#define CONV_BLOCKS 6250          // 6.4M floats / 4 / 256
#define SCAT_CHUNKS 512           // r8 fix: was 64 -> 512 (4096 scatter blocks,
#define SCAT_BLOCKS (SCAT_CHUNKS * 8)   //   ~5 serial iters/block instead of 37)
#define EPC         1172          // ceil(600000/512); last chunk clamped
#define NPS         (N_NODES / 8) // 6250 nodes per dst shard
#define GST_BLOCKS  2
#define SPLIT       8             // gather blocks per graph

__device__ __forceinline__ float bflo(unsigned int u) { return __uint_as_float(u << 16); }
__device__ __forceinline__ float bfhi(unsigned int u) { return __uint_as_float(u & 0xffff0000u); }

// ---------------------------------------------------------------------------
// Fused prep:
//  (a) conv: x fp32 -> bf16 bit-packed (row layout, float4 -> ushort4)
//  (b) sharded bucket scatter: shard = bid&7 (XCD-affinity heuristic for
//      col/deg lines under round-robin dispatch; coverage is exact for any
//      mapping: each (chunk,shard) pair is scanned by exactly one block).
//      deg[] is bucket cursor AND final in-degree.
//  (c) gstart[g] via binary search over sorted batch.
__global__ __launch_bounds__(256) void prep_kernel(
        const float* __restrict__ x, unsigned short* __restrict__ xb,
        const int* __restrict__ src, const int* __restrict__ dst,
        int* __restrict__ deg, unsigned short* __restrict__ col,
        const int* __restrict__ batch, int* __restrict__ gstart) {
    int bid = blockIdx.x, t = threadIdx.x;
    if (bid < CONV_BLOCKS) {
        int i = bid * 256 + t;                    // float4 index
        float4 f = ((const float4*)x)[i];
        ushort4 u;
        u.x = __bfloat16_as_ushort(__float2bfloat16(f.x));
        u.y = __bfloat16_as_ushort(__float2bfloat16(f.y));
        u.z = __bfloat16_as_ushort(__float2bfloat16(f.z));
        u.w = __bfloat16_as_ushort(__float2bfloat16(f.w));
        ((ushort4*)xb)[i] = u;
    } else if (bid < CONV_BLOCKS + SCAT_BLOCKS) {
        int rel   = bid - CONV_BLOCKS;            // 0..4095
        int shard = bid & 7;                      // hoped-XCD id
        int chunk = rel >> 3;                     // 0..511
        int lo = shard * NPS, hi = lo + NPS;
        int e0 = chunk * EPC;
        int e1 = e0 + EPC; if (e1 > N_EDGES) e1 = N_EDGES;
        for (int e = e0 + t; e < e1; e += 256) {
            int d = dst[e];
            if (d >= lo && d < hi) {
                int pos = atomicAdd(&deg[d], 1);
                if (pos < MAXDEG)
                    col[(size_t)d * MAXDEG + pos] = (unsigned short)src[e];
            }
        }
    } else {
        int g = (bid - CONV_BLOCKS - SCAT_BLOCKS) * 256 + t;
        if (g <= N_GRAPHS) {
            int lo = 0, hi = N_NODES;
            while (lo < hi) {
                int m = (lo + hi) >> 1;
                if (batch[m] < g) lo = m + 1; else hi = m;
            }
            gstart[g] = lo;
        }
    }
}

// ---------------------------------------------------------------------------
// Hot pass (r5-proven). Blocks < N_GRAPHS*SPLIT: node-parallel gather. One
// wave per node; lane owns feature pair {2l,2l+1} (4B -> 256B coalesced row).
// Neighbor ids: ONE coalesced ushort load + __shfl broadcast; 8/4-wide
// unrolled row loads for MLP. Register accumulate per graph, per-wave LDS
// partials, then 128 global atomics per block (512K total ~ 3us).
// Blocks >= N_GRAPHS*SPLIT: per-graph segment-sum of xb -> Px, gcnt.
__global__ __launch_bounds__(256) void gather_kernel(
        const unsigned short* __restrict__ xb, const unsigned short* __restrict__ col,
        const int* __restrict__ deg, const int* __restrict__ gstart,
        float* __restrict__ Pn, float* __restrict__ Px, int* __restrict__ gcnt) {
    __shared__ float red[4 * D_IN];   // 2 KB
    int bid  = blockIdx.x;
    int wave = threadIdx.x >> 6;
    int lane = threadIdx.x & 63;

    if (bid < N_GRAPHS * SPLIT) {
        int g = bid >> 3;             // SPLIT = 8
        int s = bid & 7;
        int n0 = gstart[g], n1 = gstart[g + 1];
        const unsigned short* xl = xb + 2 * lane;   // lane's feature-pair base

        float2 pn = make_float2(0.f, 0.f);
        for (int n = n0 + s * 4 + wave; n < n1; n += 4 * SPLIT) {
            int d = deg[n];
            int dl = (d < MAXDEG) ? d : MAXDEG;
            const unsigned short* cl = col + (size_t)n * MAXDEG;
            int cidx = (lane < dl) ? (int)cl[lane] : 0;   // one coalesced load

            float2 t = make_float2(0.f, 0.f);
            int j = 0;
            for (; j + 8 <= dl; j += 8) {
                int s0 = __shfl(cidx, j),     s1 = __shfl(cidx, j + 1);
                int s2 = __shfl(cidx, j + 2), s3 = __shfl(cidx, j + 3);
                int s4 = __shfl(cidx, j + 4), s5 = __shfl(cidx, j + 5);
                int s6 = __shfl(cidx, j + 6), s7 = __shfl(cidx, j + 7);
                unsigned int u0 = *(const unsigned int*)(xl + (size_t)s0 * D_IN);
                unsigned int u1 = *(const unsigned int*)(xl + (size_t)s1 * D_IN);
                unsigned int u2 = *(const unsigned int*)(xl + (size_t)s2 * D_IN);
                unsigned int u3 = *(const unsigned int*)(xl + (size_t)s3 * D_IN);
                unsigned int u4 = *(const unsigned int*)(xl + (size_t)s4 * D_IN);
                unsigned int u5 = *(const unsigned int*)(xl + (size_t)s5 * D_IN);
                unsigned int u6 = *(const unsigned int*)(xl + (size_t)s6 * D_IN);
                unsigned int u7 = *(const unsigned int*)(xl + (size_t)s7 * D_IN);
                t.x += bflo(u0) + bflo(u1) + bflo(u2) + bflo(u3)
                     + bflo(u4) + bflo(u5) + bflo(u6) + bflo(u7);
                t.y += bfhi(u0) + bfhi(u1) + bfhi(u2) + bfhi(u3)
                     + bfhi(u4) + bfhi(u5) + bfhi(u6) + bfhi(u7);
            }
            for (; j + 4 <= dl; j += 4) {
                int s0 = __shfl(cidx, j),     s1 = __shfl(cidx, j + 1);
                int s2 = __shfl(cidx, j + 2), s3 = __shfl(cidx, j + 3);
                unsigned int u0 = *(const unsigned int*)(xl + (size_t)s0 * D_IN);
                unsigned int u1 = *(const unsigned int*)(xl + (size_t)s1 * D_IN);
                unsigned int u2 = *(const unsigned int*)(xl + (size_t)s2 * D_IN);
                unsigned int u3 = *(const unsigned int*)(xl + (size_t)s3 * D_IN);
                t.x += bflo(u0) + bflo(u1) + bflo(u2) + bflo(u3);
                t.y += bfhi(u0) + bfhi(u1) + bfhi(u2) + bfhi(u3);
            }
            for (; j < dl; ++j) {
                int sn = __shfl(cidx, j);
                unsigned int u = *(const unsigned int*)(xl + (size_t)sn * D_IN);
                t.x += bflo(u); t.y += bfhi(u);
            }
            if (d > 0) {
                float w = __builtin_amdgcn_rcpf((float)d);
                pn.x = fmaf(t.x, w, pn.x);
                pn.y = fmaf(t.y, w, pn.y);
            }
        }
        red[wave * D_IN + 2 * lane]     = pn.x;
        red[wave * D_IN + 2 * lane + 1] = pn.y;
        __syncthreads();
        if (threadIdx.x < D_IN) {
            float v = red[threadIdx.x] + red[D_IN + threadIdx.x]
                    + red[2 * D_IN + threadIdx.x] + red[3 * D_IN + threadIdx.x];
            atomicAdd(&Pn[g * D_IN + threadIdx.x], v);
        }
    } else {
        int p  = bid - N_GRAPHS * SPLIT;          // graph id
        int n0 = gstart[p], n1 = gstart[p + 1];
        float fx = 0.f, fy = 0.f;                 // lane owns features 2l,2l+1
        for (int n = n0 + wave; n < n1; n += 4) {
            unsigned int u = *(const unsigned int*)(xb + (size_t)n * D_IN + 2 * lane);
            fx += bflo(u); fy += bfhi(u);
        }
        red[wave * D_IN + 2 * lane]     = fx;
        red[wave * D_IN + 2 * lane + 1] = fy;
        __syncthreads();
        if (threadIdx.x < D_IN) {
            float v = red[threadIdx.x] + red[D_IN + threadIdx.x]
                    + red[2 * D_IN + threadIdx.x] + red[3 * D_IN + threadIdx.x];
            Px[p * D_IN + threadIdx.x] = v;
        }
        if (threadIdx.x == 0) gcnt[p] = n1 - n0;
    }
}

// ---------------------------------------------------------------------------
// Per-graph  h = (Pn@Wl + Px@Wr)/gcnt + bl  then the 64->32->16->8->1 MLP.
__global__ void final_kernel(
        const float* __restrict__ Pn, const float* __restrict__ Px,
        const int* __restrict__ gcnt,
        const float* __restrict__ Wl, const float* __restrict__ bl,
        const float* __restrict__ Wr,
        const float* __restrict__ W0, const float* __restrict__ b0,
        const float* __restrict__ W1, const float* __restrict__ b1,
        const float* __restrict__ W2, const float* __restrict__ b2,
        const float* __restrict__ W3, const float* __restrict__ b3,
        float* __restrict__ out) {
    int g = blockIdx.x;
    int t = threadIdx.x;  // 64
    __shared__ float sp[D_IN], sx[D_IN], h[H], a0[32], a1[16], a2[8];
    sp[t]      = Pn[g * D_IN + t];
    sp[t + 64] = Pn[g * D_IN + 64 + t];
    sx[t]      = Px[g * D_IN + t];
    sx[t + 64] = Px[g * D_IN + 64 + t];
    __syncthreads();

    int ng = gcnt[g];
    float acc = 0.f;
    #pragma unroll 8
    for (int d = 0; d < D_IN; ++d)
        acc += sp[d] * Wl[d * H + t] + sx[d] * Wr[d * H + t];
    h[t] = (ng > 0) ? (acc / (float)ng + bl[t]) : 0.f;  // empty graph -> 0
    __syncthreads();

    if (t < 32) { float a = b0[t]; for (int d = 0; d < H;  ++d) a += h[d]  * W0[d * 32 + t]; a0[t] = fmaxf(a, 0.f); }
    __syncthreads();
    if (t < 16) { float a = b1[t]; for (int d = 0; d < 32; ++d) a += a0[d] * W1[d * 16 + t]; a1[t] = fmaxf(a, 0.f); }
    __syncthreads();
    if (t < 8)  { float a = b2[t]; for (int d = 0; d < 16; ++d) a += a1[d] * W2[d * 8 + t];  a2[t] = fmaxf(a, 0.f); }
    __syncthreads();
    if (t == 0) { float a = b3[0]; for (int d = 0; d < 8;  ++d) a += a2[d] * W3[d]; out[g] = a; }
}

// ---------------------------------------------------------------------------
extern "C" void kernel_launch(void* const* d_in, const int* in_sizes, int n_in,
                              void* d_out, int out_size, void* d_ws, size_t ws_size,
                              hipStream_t stream) {
    const float* x     = (const float*)d_in[0];
    const int*   ei    = (const int*)  d_in[1];   // [2, N_EDGES]: row0=src, row1=dst
    const int*   batch = (const int*)  d_in[2];
    const float* Wl    = (const float*)d_in[3];
    const float* bl    = (const float*)d_in[4];
    const float* Wr    = (const float*)d_in[5];
    const float* W0    = (const float*)d_in[6];
    const float* b0    = (const float*)d_in[7];
    const float* W1    = (const float*)d_in[8];
    const float* b1    = (const float*)d_in[9];
    const float* W2    = (const float*)d_in[10];
    const float* b2    = (const float*)d_in[11];
    const float* W3    = (const float*)d_in[12];
    const float* b3    = (const float*)d_in[13];
    float* out = (float*)d_out;

    // ws layout:
    //  [deg 200000 -> pad 200704][Pn 256000 -> 456704]          <- memset 0
    //  [Px @460800 256000][gcnt @716800][gstart @720896]
    //  [col ushort @724992 4.8MB][xb @5524992 12.8MB]
    char* ws = (char*)d_ws;
    int*            deg    = (int*)(ws + 0);
    float*          Pn     = (float*)(ws + 200704);
    float*          Px     = (float*)(ws + 460800);
    int*            gcnt   = (int*)(ws + 716800);
    int*            gstart = (int*)(ws + 720896);
    unsigned short* col    = (unsigned short*)(ws + 724992);
    unsigned short* xb     = (unsigned short*)(ws + 5524992);

    hipMemsetAsync(ws, 0, 456704, stream);  // deg + pad + Pn

    prep_kernel<<<CONV_BLOCKS + SCAT_BLOCKS + GST_BLOCKS, 256, 0, stream>>>(
        x, xb, ei, ei + N_EDGES, deg, col, batch, gstart);
    gather_kernel<<<N_GRAPHS * SPLIT + N_GRAPHS, 256, 0, stream>>>(
        xb, col, deg, gstart, Pn, Px, gcnt);
    final_kernel<<<N_GRAPHS, 64, 0, stream>>>(Pn, Px, gcnt, Wl, bl, Wr,
                                              W0, b0, W1, b1, W2, b2, W3, b3, out);
}